// Round 1
// baseline (3649.366 us; speedup 1.0000x reference)
//
#include <hip/hip_runtime.h>
#include <stdint.h>

typedef unsigned short u16;
typedef unsigned int   u32;
typedef __attribute__((ext_vector_type(8))) __bf16 bf16x8;
typedef __attribute__((ext_vector_type(4))) float  f32x4;
typedef __attribute__((ext_vector_type(8))) u16    u16x8;
typedef __attribute__((ext_vector_type(4))) u16    u16x4;
typedef __attribute__((ext_vector_type(2))) u32    u32x2;

__device__ __forceinline__ u16 f2bf(float f) {
    u32 u = __float_as_uint(f);
    u32 r = (u + 0x7fffu + ((u >> 16) & 1u)) >> 16;   // RNE
    return (u16)r;
}
__device__ __forceinline__ float bf2f(u16 v) { return __uint_as_float(((u32)v) << 16); }

// ---------------------------------------------------------------- prep: cast weights to bf16
__global__ void k_prep(const float* __restrict__ W_ih, const float* __restrict__ W_hh,
                       u16* __restrict__ Wf, u16* __restrict__ Whh) {
    int i = blockIdx.x * 256 + threadIdx.x;
    if (i < 768 * 512) { int o = i >> 9, k = i & 511; Wf[i] = f2bf(W_ih[o * 514 + k]); }
    if (i < 768 * 256) { Whh[i] = f2bf(W_hh[i]); }
}

// ---------------------------------------------------------------- feature GEMM: Gf[t][b][o] = feat @ Wf^T + b_ih
// M = B*T = 262144 (rows m = b*256 + t), N = 768, K = 512. 128x128 tile, BK=64, 4 waves.
template<typename ST>
__global__ __launch_bounds__(256) void k_gemm(const float* __restrict__ feat,
                                              const u16* __restrict__ Wf,
                                              const float* __restrict__ bih,
                                              ST* __restrict__ Gf) {
    __shared__ u16 As[128 * 64];
    __shared__ u16 Bs[128 * 64];
    const int tid = threadIdx.x;
    const int l = tid & 63, wv = tid >> 6;
    const int wr = wv >> 1, wc = wv & 1;
    const int lb = l & 15, lq = l >> 4;
    const int n0 = blockIdx.x * 128;      // N (gate-row) tile — fastest so 6 sharers of A co-run
    const int m0 = blockIdx.y * 128;      // M ((b,t)) tile
    const int srow = tid >> 1, scol = (tid & 1) * 32;

    f32x4 acc[4][4] = {};

    for (int k0 = 0; k0 < 512; k0 += 64) {
        __syncthreads();
        const float* ga = feat + (size_t)(m0 + srow) * 512 + k0 + scol;
        const u16*   gb = Wf + (n0 + srow) * 512 + k0 + scol;
        char* arow = (char*)As + srow * 128;
        char* brow = (char*)Bs + srow * 128;
        const int swz = (srow & 7) << 4;
#pragma unroll
        for (int i = 0; i < 4; ++i) {
            float4 f0 = *(const float4*)(ga + i * 8);
            float4 f1 = *(const float4*)(ga + i * 8 + 4);
            u16x8 v;
            v[0] = f2bf(f0.x); v[1] = f2bf(f0.y); v[2] = f2bf(f0.z); v[3] = f2bf(f0.w);
            v[4] = f2bf(f1.x); v[5] = f2bf(f1.y); v[6] = f2bf(f1.z); v[7] = f2bf(f1.w);
            *(u16x8*)(arow + (((scol + i * 8) * 2) ^ swz)) = v;
            u16x8 w8 = *(const u16x8*)(gb + i * 8);
            *(u16x8*)(brow + (((scol + i * 8) * 2) ^ swz)) = w8;
        }
        __syncthreads();
#pragma unroll
        for (int kc = 0; kc < 2; ++kc) {
            bf16x8 af[4], bfr[4];
#pragma unroll
            for (int mi = 0; mi < 4; ++mi) {
                int row = wr * 64 + mi * 16 + lb;
                af[mi] = *(const bf16x8*)((char*)As + row * 128 + (((kc * 32 + lq * 8) * 2) ^ ((row & 7) << 4)));
            }
#pragma unroll
            for (int ni = 0; ni < 4; ++ni) {
                int row = wc * 64 + ni * 16 + lb;
                bfr[ni] = *(const bf16x8*)((char*)Bs + row * 128 + (((kc * 32 + lq * 8) * 2) ^ ((row & 7) << 4)));
            }
#pragma unroll
            for (int mi = 0; mi < 4; ++mi)
#pragma unroll
                for (int ni = 0; ni < 4; ++ni)
                    acc[mi][ni] = __builtin_amdgcn_mfma_f32_16x16x32_bf16(af[mi], bfr[ni], acc[mi][ni], 0, 0, 0);
        }
    }
    // epilogue: D col = lane&15 (o), row = 4*(lane>>4)+j (m). Gf layout (T, B, 768).
#pragma unroll
    for (int ni = 0; ni < 4; ++ni) {
        int o = n0 + wc * 64 + ni * 16 + lb;
        float bi = bih[o];
#pragma unroll
        for (int mi = 0; mi < 4; ++mi) {
#pragma unroll
            for (int j = 0; j < 4; ++j) {
                int m = m0 + wr * 64 + mi * 16 + lq * 4 + j;
                int bb = m >> 8, tt = m & 255;
                size_t idx = (size_t)((tt << 10) + bb) * 768 + o;
                float v = acc[mi][ni][j] + bi;
                if constexpr (sizeof(ST) == 4) Gf[idx] = v; else Gf[idx] = f2bf(v);
            }
        }
    }
}

// ---------------------------------------------------------------- recurrence: 64 blocks x 16 batches, 8 waves
// wave w owns gate-row tiles {2w, 2w+1, 256+.., 512+..}; lane handles units u = (2w+ut)*16 + (l>>4)*4 + j, batch l&15.
template<typename ST>
__global__ __launch_bounds__(512, 2) void k_rnn(const float* __restrict__ lastc,
                                                const float* __restrict__ W_ih,
                                                const float* __restrict__ bhh_g,
                                                const float* __restrict__ Wp,
                                                const float* __restrict__ bp,
                                                const u16* __restrict__ Whh,
                                                const ST* __restrict__ Gf,
                                                float* __restrict__ out) {
    __shared__ u16 hbf[16 * 264];                 // [batch][u], padded 256->264 (bank spread)
    __shared__ float coordL[16][2];
    __shared__ float dPart[8][16][2];
    const int tid = threadIdx.x, l = tid & 63, wv = tid >> 6;
    const int lb = l & 15, lq = l >> 4;
    const int bb = blockIdx.x << 4;

    float bhh[3][2][4], wcx[3][2][4], wcy[3][2][4], wp0[2][4], wp1[2][4];
#pragma unroll
    for (int g = 0; g < 3; ++g)
#pragma unroll
        for (int ut = 0; ut < 2; ++ut)
#pragma unroll
            for (int j = 0; j < 4; ++j) {
                int row = g * 256 + (2 * wv + ut) * 16 + lq * 4 + j;
                bhh[g][ut][j] = bhh_g[row];
                wcx[g][ut][j] = W_ih[row * 514 + 512];
                wcy[g][ut][j] = W_ih[row * 514 + 513];
            }
#pragma unroll
    for (int ut = 0; ut < 2; ++ut)
#pragma unroll
        for (int j = 0; j < 4; ++j) {
            int u = (2 * wv + ut) * 16 + lq * 4 + j;
            wp0[ut][j] = Wp[u];
            wp1[ut][j] = Wp[256 + u];
        }
    float hreg[2][4] = {};

    for (int i = tid; i < 16 * 264 / 2; i += 512) ((u32*)hbf)[i] = 0u;
    if (tid < 32) coordL[tid >> 1][tid & 1] = lastc[(bb + (tid >> 1)) * 2 + (tid & 1)];
    float bpc = 0.f;
    if (tid < 32) bpc = bp[tid & 1];
    __syncthreads();

    const u16* wb[3][2];
#pragma unroll
    for (int g = 0; g < 3; ++g)
#pragma unroll
        for (int ut = 0; ut < 2; ++ut)
            wb[g][ut] = Whh + (size_t)(g * 256 + (2 * wv + ut) * 16 + lb) * 256 + lq * 8;
    const u16* hp = hbf + lb * 264 + lq * 8;

    for (int t = 0; t < 256; ++t) {
        // --- Gf prefetch (independent of LDS; completes by S1's vmcnt drain) ---
        float gf[3][2][4];
        const ST* gr = Gf + (size_t)(t * 1024 + bb + lb) * 768 + lq * 4;
#pragma unroll
        for (int g = 0; g < 3; ++g)
#pragma unroll
            for (int ut = 0; ut < 2; ++ut) {
                int off = g * 256 + (2 * wv + ut) * 16;
                if constexpr (sizeof(ST) == 4) {
                    float4 v = *(const float4*)(gr + off);
                    gf[g][ut][0] = v.x; gf[g][ut][1] = v.y; gf[g][ut][2] = v.z; gf[g][ut][3] = v.w;
                } else {
                    u16x4 v = *(const u16x4*)(gr + off);
#pragma unroll
                    for (int j = 0; j < 4; ++j) gf[g][ut][j] = bf2f(v[j]);
                }
            }

        // --- gh = W_hh @ h : 48 MFMA per wave, W fragments stream from L2 ---
        f32x4 acc[3][2] = {};
#pragma unroll
        for (int kc = 0; kc < 8; ++kc) {
            bf16x8 hb = *(const bf16x8*)(hp + kc * 32);
#pragma unroll
            for (int g = 0; g < 3; ++g)
#pragma unroll
                for (int ut = 0; ut < 2; ++ut) {
                    bf16x8 wfr = *(const bf16x8*)(wb[g][ut] + kc * 32);
                    acc[g][ut] = __builtin_amdgcn_mfma_f32_16x16x32_bf16(wfr, hb, acc[g][ut], 0, 0, 0);
                }
        }
        __syncthreads();   // S1: all reads of hbf done -> safe to overwrite

        // --- gates, h update, disp partials (all in registers) ---
        float cx = coordL[lb][0], cy = coordL[lb][1];
        float pd0 = 0.f, pd1 = 0.f;
#pragma unroll
        for (int ut = 0; ut < 2; ++ut) {
            u16 hpk[4];
#pragma unroll
            for (int j = 0; j < 4; ++j) {
                float gir = gf[0][ut][j] + wcx[0][ut][j] * cx + wcy[0][ut][j] * cy;
                float giz = gf[1][ut][j] + wcx[1][ut][j] * cx + wcy[1][ut][j] * cy;
                float gin = gf[2][ut][j] + wcx[2][ut][j] * cx + wcy[2][ut][j] * cy;
                float ghr = acc[0][ut][j] + bhh[0][ut][j];
                float ghz = acc[1][ut][j] + bhh[1][ut][j];
                float ghn = acc[2][ut][j] + bhh[2][ut][j];
                float r = 1.f / (1.f + __expf(-(gir + ghr)));
                float z = 1.f / (1.f + __expf(-(giz + ghz)));
                float xn = gin + r * ghn;
                float e = __expf(-2.f * fabsf(xn));
                float th = (1.f - e) / (1.f + e);
                th = (xn >= 0.f) ? th : -th;
                float hn = (1.f - z) * th + z * hreg[ut][j];
                hreg[ut][j] = hn;
                pd0 += wp0[ut][j] * hn;
                pd1 += wp1[ut][j] * hn;
                hpk[j] = f2bf(hn);
            }
            int ub = (2 * wv + ut) * 16 + lq * 4;
            u32x2 pv;
            pv.x = (u32)hpk[0] | ((u32)hpk[1] << 16);
            pv.y = (u32)hpk[2] | ((u32)hpk[3] << 16);
            *(u32x2*)((char*)hbf + lb * 528 + ub * 2) = pv;
        }
        pd0 += __shfl_xor(pd0, 16); pd0 += __shfl_xor(pd0, 32);
        pd1 += __shfl_xor(pd1, 16); pd1 += __shfl_xor(pd1, 32);
        if (l < 16) { dPart[wv][l][0] = pd0; dPart[wv][l][1] = pd1; }
        __syncthreads();   // S2: hbf + dPart written

        if (tid < 32) {
            int b = tid >> 1, c = tid & 1;
            float d = bpc;
#pragma unroll
            for (int w8 = 0; w8 < 8; ++w8) d += dPart[w8][b][c];
            out[((size_t)(bb + b) * 256 + t) * 2 + c] = d;
            coordL[b][c] += d;
        }
        __syncthreads();   // S3: coordL updated, dPart free
    }
}

// ----------------------------------------------------------------
extern "C" void kernel_launch(void* const* d_in, const int* in_sizes, int n_in,
                              void* d_out, int out_size, void* d_ws, size_t ws_size,
                              hipStream_t stream) {
    const float* feat   = (const float*)d_in[0];
    const float* lastc  = (const float*)d_in[1];
    const float* W_ih   = (const float*)d_in[2];
    const float* W_hh   = (const float*)d_in[3];
    const float* b_ih   = (const float*)d_in[4];
    const float* b_hh   = (const float*)d_in[5];
    const float* W_proj = (const float*)d_in[6];
    const float* b_proj = (const float*)d_in[7];
    float* out = (float*)d_out;

    char* ws = (char*)d_ws;
    u16* Wf  = (u16*)ws;                                   // 768*512 bf16
    u16* Whh = (u16*)(ws + (size_t)768 * 512 * 2);         // 768*256 bf16
    const size_t gf_off = (size_t)768 * 512 * 2 + (size_t)768 * 256 * 2;
    const size_t need32 = gf_off + (size_t)262144 * 768 * 4;

    k_prep<<<1536, 256, 0, stream>>>(W_ih, W_hh, Wf, Whh);

    if (ws_size >= need32) {
        float* Gf = (float*)(ws + gf_off);
        k_gemm<float><<<dim3(6, 2048), 256, 0, stream>>>(feat, Wf, b_ih, Gf);
        k_rnn<float><<<64, 512, 0, stream>>>(lastc, W_ih, b_hh, W_proj, b_proj, Whh, Gf, out);
    } else {
        u16* Gf = (u16*)(ws + gf_off);
        k_gemm<u16><<<dim3(6, 2048), 256, 0, stream>>>(feat, Wf, b_ih, Gf);
        k_rnn<u16><<<64, 512, 0, stream>>>(lastc, W_ih, b_hh, W_proj, b_proj, Whh, Gf, out);
    }
}

// Round 2
// 1482.054 us; speedup vs baseline: 2.4624x; 2.4624x over previous
//
#include <hip/hip_runtime.h>
#include <stdint.h>

typedef unsigned short u16;
typedef unsigned int   u32;
typedef __attribute__((ext_vector_type(8))) __bf16 bf16x8;
typedef __attribute__((ext_vector_type(4))) float  f32x4;
typedef __attribute__((ext_vector_type(8))) u16    u16x8;
typedef __attribute__((ext_vector_type(4))) u16    u16x4;
typedef __attribute__((ext_vector_type(2))) u32    u32x2;

__device__ __forceinline__ u16 f2bf(float f) {
    u32 u = __float_as_uint(f);
    u32 r = (u + 0x7fffu + ((u >> 16) & 1u)) >> 16;   // RNE
    return (u16)r;
}
__device__ __forceinline__ float bf2f(u16 v) { return __uint_as_float(((u32)v) << 16); }
__device__ __forceinline__ bf16x8 as_bf(u16x8 x) { union { u16x8 a; bf16x8 b; } u; u.a = x; return u.b; }
__device__ __forceinline__ void gload_lds16(const void* g, void* l) {
    __builtin_amdgcn_global_load_lds((const __attribute__((address_space(1))) void*)g,
                                     (__attribute__((address_space(3))) void*)l, 16, 0, 0);
}

// ---------------------------------------------------------------- prep: weights -> bf16, bias fold
__global__ void k_prep(const float* __restrict__ W_ih, const float* __restrict__ W_hh,
                       const float* __restrict__ b_ih, const float* __restrict__ b_hh,
                       u16* __restrict__ Wf, u16* __restrict__ Whh, float* __restrict__ bsum) {
    int i = blockIdx.x * 256 + threadIdx.x;
    if (i < 768 * 512) { int o = i >> 9, k = i & 511; Wf[i] = f2bf(W_ih[o * 514 + k]); }
    if (i < 768 * 256) { Whh[i] = f2bf(W_hh[i]); }
    if (i < 768)       { bsum[i] = b_ih[i] + (i < 512 ? b_hh[i] : 0.f); }  // fold b_hh for r,z only
}

// ---------------------------------------------------------------- cast features fp32 -> bf16
__global__ void k_cast(const float* __restrict__ f, u16* __restrict__ o) {
    const size_t N8 = (size_t)262144 * 512 / 8;
    for (size_t i = (size_t)blockIdx.x * 256 + threadIdx.x; i < N8; i += (size_t)gridDim.x * 256) {
        float4 a = ((const float4*)f)[i * 2];
        float4 b = ((const float4*)f)[i * 2 + 1];
        u16x8 v;
        v[0] = f2bf(a.x); v[1] = f2bf(a.y); v[2] = f2bf(a.z); v[3] = f2bf(a.w);
        v[4] = f2bf(b.x); v[5] = f2bf(b.y); v[6] = f2bf(b.z); v[7] = f2bf(b.w);
        ((u16x8*)o)[i] = v;
    }
}

// ---------------------------------------------------------------- feature GEMM (bf16 A via global_load_lds)
// Gf[t][b][o] = feat@Wf^T + bsum. M=262144 (m=b*256+t), N=768, K=512. 128x128, BK=64, 4 waves.
__global__ __launch_bounds__(256) void k_gemm(const u16* __restrict__ featbf,
                                              const u16* __restrict__ Wf,
                                              const float* __restrict__ bsum,
                                              float* __restrict__ Gf) {
    __shared__ u16 As[128 * 64];
    __shared__ u16 Bs[128 * 64];
    const int tid = threadIdx.x;
    const int l = tid & 63, wv = tid >> 6;
    const int wr = wv >> 1, wc = wv & 1;
    const int lb = l & 15, lq = l >> 4;
    const int n0 = blockIdx.x * 128;
    const int m0 = blockIdx.y * 128;
    const int rl = l >> 3;                  // row within 8-row chunk
    const int c16 = (l & 7) * 16;           // 16B column within row
    const int sswz = (rl & 7) << 4;

    f32x4 acc[4][4] = {};

    for (int k0 = 0; k0 < 512; k0 += 64) {
        __syncthreads();
#pragma unroll
        for (int i = 0; i < 4; ++i) {
            int ci = wv * 4 + i;
            int r = ci * 8 + rl;
            const char* sa = (const char*)(featbf + (size_t)(m0 + r) * 512) + k0 * 2 + (c16 ^ sswz);
            gload_lds16(sa, (char*)As + ci * 1024);
            const char* sb = (const char*)(Wf + (size_t)(n0 + r) * 512) + k0 * 2 + (c16 ^ sswz);
            gload_lds16(sb, (char*)Bs + ci * 1024);
        }
        __syncthreads();
#pragma unroll
        for (int kc = 0; kc < 2; ++kc) {
            bf16x8 af[4], bfr[4];
#pragma unroll
            for (int mi = 0; mi < 4; ++mi) {
                int row = wr * 64 + mi * 16 + lb;
                af[mi] = *(const bf16x8*)((char*)As + row * 128 + (((kc * 32 + lq * 8) * 2) ^ ((row & 7) << 4)));
            }
#pragma unroll
            for (int ni = 0; ni < 4; ++ni) {
                int row = wc * 64 + ni * 16 + lb;
                bfr[ni] = *(const bf16x8*)((char*)Bs + row * 128 + (((kc * 32 + lq * 8) * 2) ^ ((row & 7) << 4)));
            }
#pragma unroll
            for (int mi = 0; mi < 4; ++mi)
#pragma unroll
                for (int ni = 0; ni < 4; ++ni)
                    acc[mi][ni] = __builtin_amdgcn_mfma_f32_16x16x32_bf16(af[mi], bfr[ni], acc[mi][ni], 0, 0, 0);
        }
    }
#pragma unroll
    for (int ni = 0; ni < 4; ++ni) {
        int o = n0 + wc * 64 + ni * 16 + lb;
        float bi = bsum[o];
#pragma unroll
        for (int mi = 0; mi < 4; ++mi) {
#pragma unroll
            for (int j = 0; j < 4; ++j) {
                int m = m0 + wr * 64 + mi * 16 + lq * 4 + j;
                int bb = m >> 8, tt = m & 255;
                Gf[(size_t)((tt << 10) + bb) * 768 + o] = acc[mi][ni][j] + bi;
            }
        }
    }
}

// ---------------------------------------------------------------- legacy GEMM (fp32 loads), small-ws fallback
template<typename ST>
__global__ __launch_bounds__(256) void k_gemm_legacy(const float* __restrict__ feat,
                                                     const u16* __restrict__ Wf,
                                                     const float* __restrict__ bsum,
                                                     ST* __restrict__ Gf) {
    __shared__ u16 As[128 * 64];
    __shared__ u16 Bs[128 * 64];
    const int tid = threadIdx.x;
    const int l = tid & 63, wv = tid >> 6;
    const int wr = wv >> 1, wc = wv & 1;
    const int lb = l & 15, lq = l >> 4;
    const int n0 = blockIdx.x * 128;
    const int m0 = blockIdx.y * 128;
    const int srow = tid >> 1, scol = (tid & 1) * 32;

    f32x4 acc[4][4] = {};

    for (int k0 = 0; k0 < 512; k0 += 64) {
        __syncthreads();
        const float* ga = feat + (size_t)(m0 + srow) * 512 + k0 + scol;
        const u16*   gb = Wf + (n0 + srow) * 512 + k0 + scol;
        char* arow = (char*)As + srow * 128;
        char* brow = (char*)Bs + srow * 128;
        const int swz = (srow & 7) << 4;
#pragma unroll
        for (int i = 0; i < 4; ++i) {
            float4 f0 = *(const float4*)(ga + i * 8);
            float4 f1 = *(const float4*)(ga + i * 8 + 4);
            u16x8 v;
            v[0] = f2bf(f0.x); v[1] = f2bf(f0.y); v[2] = f2bf(f0.z); v[3] = f2bf(f0.w);
            v[4] = f2bf(f1.x); v[5] = f2bf(f1.y); v[6] = f2bf(f1.z); v[7] = f2bf(f1.w);
            *(u16x8*)(arow + (((scol + i * 8) * 2) ^ swz)) = v;
            u16x8 w8 = *(const u16x8*)(gb + i * 8);
            *(u16x8*)(brow + (((scol + i * 8) * 2) ^ swz)) = w8;
        }
        __syncthreads();
#pragma unroll
        for (int kc = 0; kc < 2; ++kc) {
            bf16x8 af[4], bfr[4];
#pragma unroll
            for (int mi = 0; mi < 4; ++mi) {
                int row = wr * 64 + mi * 16 + lb;
                af[mi] = *(const bf16x8*)((char*)As + row * 128 + (((kc * 32 + lq * 8) * 2) ^ ((row & 7) << 4)));
            }
#pragma unroll
            for (int ni = 0; ni < 4; ++ni) {
                int row = wc * 64 + ni * 16 + lb;
                bfr[ni] = *(const bf16x8*)((char*)Bs + row * 128 + (((kc * 32 + lq * 8) * 2) ^ ((row & 7) << 4)));
            }
#pragma unroll
            for (int mi = 0; mi < 4; ++mi)
#pragma unroll
                for (int ni = 0; ni < 4; ++ni)
                    acc[mi][ni] = __builtin_amdgcn_mfma_f32_16x16x32_bf16(af[mi], bfr[ni], acc[mi][ni], 0, 0, 0);
        }
    }
#pragma unroll
    for (int ni = 0; ni < 4; ++ni) {
        int o = n0 + wc * 64 + ni * 16 + lb;
        float bi = bsum[o];
#pragma unroll
        for (int mi = 0; mi < 4; ++mi) {
#pragma unroll
            for (int j = 0; j < 4; ++j) {
                int m = m0 + wr * 64 + mi * 16 + lq * 4 + j;
                int bb = m >> 8, tt = m & 255;
                size_t idx = (size_t)((tt << 10) + bb) * 768 + o;
                float v = acc[mi][ni][j] + bi;
                if constexpr (sizeof(ST) == 4) Gf[idx] = v; else Gf[idx] = f2bf(v);
            }
        }
    }
}

// ---------------------------------------------------------------- recurrence: W_hh resident (regs kc0-4, LDS kc5-7)
// 64 blocks x 16 batches, 8 waves. Wave w owns row-tiles (2w,2w+1) per gate.
// Coord terms folded into MFMA via k-extension (k=256:cx, 257:cy); n-gate coord in separate acc.
template<typename ST>
__global__ __launch_bounds__(512, 2) void k_rnn(const float* __restrict__ lastc,
                                                const float* __restrict__ W_ih,
                                                const float* __restrict__ bhh_g,
                                                const float* __restrict__ Wp,
                                                const float* __restrict__ bp,
                                                const u16* __restrict__ Whh,
                                                const ST* __restrict__ Gf,
                                                float* __restrict__ out) {
    __shared__ u16 Wlds[3 * 768 * 32];       // kc 5..7: [kcs][row][k0..31], 144 KB
    __shared__ u16 hbf[16 * 320];            // [batch][k 0..319]: h(0..255) + ext(256..319), XOR-swizzled
    __shared__ float wpL[256 * 2];           // [u][c]
    __shared__ float coordL[16 * 2];
    __shared__ float dPart[8 * 16 * 2];

    const int tid = threadIdx.x, l = tid & 63, wv = tid >> 6;
    const int lb = l & 15, lq = l >> 4;
    const int bb = blockIdx.x << 4;
    const int swz = (lb & 7) << 4;

    // resident W fragments + coord fragments + n-gate b_hh
    bf16x8 wres[5][3][2];
    bf16x8 wcf[3][2];
    float bhhn[2][4];
#pragma unroll
    for (int g = 0; g < 3; ++g)
#pragma unroll
        for (int ut = 0; ut < 2; ++ut) {
            int row = g * 256 + (2 * wv + ut) * 16 + lb;
#pragma unroll
            for (int kc = 0; kc < 5; ++kc)
                wres[kc][g][ut] = *(const bf16x8*)(Whh + row * 256 + kc * 32 + lq * 8);
            u16x8 cf = {0, 0, 0, 0, 0, 0, 0, 0};
            if (lq == 0) {
                cf[0] = f2bf(W_ih[row * 514 + 512]);
                cf[1] = f2bf(W_ih[row * 514 + 513]);
            }
            wcf[g][ut] = as_bf(cf);
        }
#pragma unroll
    for (int ut = 0; ut < 2; ++ut)
#pragma unroll
        for (int j = 0; j < 4; ++j)
            bhhn[ut][j] = bhh_g[512 + (2 * wv + ut) * 16 + lq * 4 + j];

    // stage Wlds (kc 5..7), zero hbf, wpL
    for (int i = tid; i < 3 * 768 * 16; i += 512) {       // u32 units
        int kcs = i / (768 * 16), rem = i - kcs * (768 * 16);
        int row = rem >> 4, kh = rem & 15;
        ((u32*)Wlds)[i] = *(const u32*)(Whh + row * 256 + (5 + kcs) * 32 + kh * 2);
    }
    for (int i = tid; i < 16 * 320 / 2; i += 512) ((u32*)hbf)[i] = 0u;
    if (tid < 256) { wpL[tid * 2] = Wp[tid]; wpL[tid * 2 + 1] = Wp[256 + tid]; }
    float bpc = (tid < 32) ? bp[tid & 1] : 0.f;
    __syncthreads();
    if (tid < 32) {
        int b = tid >> 1, c = tid & 1;
        float cc = lastc[(bb + b) * 2 + c];
        coordL[b * 2 + c] = cc;
        *(u16*)((char*)hbf + b * 640 + 512 + ((c * 2) ^ ((b & 7) << 4))) = f2bf(cc);
    }
    __syncthreads();

    float hreg[2][4] = {};
    const ST* gr = Gf + (size_t)(bb + lb) * 768 + lq * 4;
    const char* hrow = (const char*)hbf + lb * 640;

    for (int t = 0; t < 256; ++t) {
        // Gf prefetch (HBM latency hidden under MFMA phase)
        float gf[3][2][4];
#pragma unroll
        for (int g = 0; g < 3; ++g)
#pragma unroll
            for (int ut = 0; ut < 2; ++ut) {
                int off = g * 256 + (2 * wv + ut) * 16;
                if constexpr (sizeof(ST) == 4) {
                    float4 v = *(const float4*)(gr + off);
                    gf[g][ut][0] = v.x; gf[g][ut][1] = v.y; gf[g][ut][2] = v.z; gf[g][ut][3] = v.w;
                } else {
                    u16x4 v = *(const u16x4*)(gr + off);
#pragma unroll
                    for (int j = 0; j < 4; ++j) gf[g][ut][j] = bf2f(v[j]);
                }
            }

        // gh = W_hh @ h (+ coord via k-ext)
        f32x4 acc[3][2] = {};
        f32x4 accC[2] = {};
#pragma unroll
        for (int kc = 0; kc < 5; ++kc) {
            bf16x8 hb = *(const bf16x8*)(hrow + ((kc * 64 + lq * 16) ^ swz));
#pragma unroll
            for (int g = 0; g < 3; ++g)
#pragma unroll
                for (int ut = 0; ut < 2; ++ut)
                    acc[g][ut] = __builtin_amdgcn_mfma_f32_16x16x32_bf16(wres[kc][g][ut], hb, acc[g][ut], 0, 0, 0);
        }
#pragma unroll
        for (int kcs = 0; kcs < 3; ++kcs) {
            bf16x8 hb = *(const bf16x8*)(hrow + (((5 + kcs) * 64 + lq * 16) ^ swz));
#pragma unroll
            for (int g = 0; g < 3; ++g)
#pragma unroll
                for (int ut = 0; ut < 2; ++ut) {
                    int row = g * 256 + (2 * wv + ut) * 16 + lb;
                    bf16x8 wl = *(const bf16x8*)((const char*)Wlds + (size_t)(kcs * 768 + row) * 64 + lq * 16);
                    acc[g][ut] = __builtin_amdgcn_mfma_f32_16x16x32_bf16(wl, hb, acc[g][ut], 0, 0, 0);
                }
        }
        {
            bf16x8 hbE = *(const bf16x8*)(hrow + 512 + ((lq * 16) ^ swz));
#pragma unroll
            for (int ut = 0; ut < 2; ++ut) {
                acc[0][ut] = __builtin_amdgcn_mfma_f32_16x16x32_bf16(wcf[0][ut], hbE, acc[0][ut], 0, 0, 0);
                acc[1][ut] = __builtin_amdgcn_mfma_f32_16x16x32_bf16(wcf[1][ut], hbE, acc[1][ut], 0, 0, 0);
                accC[ut]   = __builtin_amdgcn_mfma_f32_16x16x32_bf16(wcf[2][ut], hbE, accC[ut],   0, 0, 0);
            }
        }
        __syncthreads();   // S1: hbf reads done

        // gates + h update + disp partials (registers)
        float pd0 = 0.f, pd1 = 0.f;
#pragma unroll
        for (int ut = 0; ut < 2; ++ut) {
            int ub = (2 * wv + ut) * 16 + lq * 4;
            float4 wpa = *(const float4*)(wpL + ub * 2);
            float4 wpb = *(const float4*)(wpL + ub * 2 + 4);
            u16 hpk[4];
#pragma unroll
            for (int j = 0; j < 4; ++j) {
                float r = 1.f / (1.f + __expf(-(gf[0][ut][j] + acc[0][ut][j])));
                float z = 1.f / (1.f + __expf(-(gf[1][ut][j] + acc[1][ut][j])));
                float ghn = acc[2][ut][j] + bhhn[ut][j];
                float xn = gf[2][ut][j] + accC[ut][j] + r * ghn;
                float e = __expf(-2.f * fabsf(xn));
                float th = (1.f - e) / (1.f + e);
                th = (xn >= 0.f) ? th : -th;
                float hn = (1.f - z) * th + z * hreg[ut][j];
                hreg[ut][j] = hn;
                float w0 = (j == 0) ? wpa.x : (j == 1) ? wpa.z : (j == 2) ? wpb.x : wpb.z;
                float w1 = (j == 0) ? wpa.y : (j == 1) ? wpa.w : (j == 2) ? wpb.y : wpb.w;
                pd0 += w0 * hn;
                pd1 += w1 * hn;
                hpk[j] = f2bf(hn);
            }
            u32x2 pv;
            pv.x = (u32)hpk[0] | ((u32)hpk[1] << 16);
            pv.y = (u32)hpk[2] | ((u32)hpk[3] << 16);
            *(u32x2*)((char*)hbf + lb * 640 + ((ub * 2) ^ swz)) = pv;
        }
        pd0 += __shfl_xor(pd0, 16); pd0 += __shfl_xor(pd0, 32);
        pd1 += __shfl_xor(pd1, 16); pd1 += __shfl_xor(pd1, 32);
        if (l < 16) { dPart[(wv * 16 + l) * 2] = pd0; dPart[(wv * 16 + l) * 2 + 1] = pd1; }
        __syncthreads();   // S2: hbf + dPart written

        if (tid < 32) {
            int b = tid >> 1, c = tid & 1;
            float d = bpc;
#pragma unroll
            for (int w8 = 0; w8 < 8; ++w8) d += dPart[(w8 * 16 + b) * 2 + c];
            out[((size_t)(bb + b) * 256 + t) * 2 + c] = d;
            float nc = coordL[b * 2 + c] + d;
            coordL[b * 2 + c] = nc;
            *(u16*)((char*)hbf + b * 640 + 512 + ((c * 2) ^ ((b & 7) << 4))) = f2bf(nc);
        }
        __syncthreads();   // S3: coord ext updated
        gr += (size_t)1024 * 768;
    }
}

// ----------------------------------------------------------------
extern "C" void kernel_launch(void* const* d_in, const int* in_sizes, int n_in,
                              void* d_out, int out_size, void* d_ws, size_t ws_size,
                              hipStream_t stream) {
    const float* feat   = (const float*)d_in[0];
    const float* lastc  = (const float*)d_in[1];
    const float* W_ih   = (const float*)d_in[2];
    const float* W_hh   = (const float*)d_in[3];
    const float* b_ih   = (const float*)d_in[4];
    const float* b_hh   = (const float*)d_in[5];
    const float* W_proj = (const float*)d_in[6];
    const float* b_proj = (const float*)d_in[7];
    float* out = (float*)d_out;

    char* ws = (char*)d_ws;
    u16*   Wf    = (u16*)ws;                                    // 768*512 bf16
    u16*   Whh   = (u16*)(ws + 786432);                         // 768*256 bf16
    float* bsum  = (float*)(ws + 786432 + 393216);              // 768 f32
    const size_t off_fb = 786432 + 393216 + 3072;
    u16*   featbf = (u16*)(ws + off_fb);                        // 262144*512 bf16
    const size_t off_gf_full = off_fb + (size_t)262144 * 512 * 2;
    const size_t need_full  = off_gf_full + (size_t)262144 * 768 * 4;
    const size_t need_tier2 = off_fb + (size_t)262144 * 768 * 4;
    const size_t need_tier3 = off_fb + (size_t)262144 * 768 * 2;

    k_prep<<<1536, 256, 0, stream>>>(W_ih, W_hh, b_ih, b_hh, Wf, Whh, bsum);

    if (ws_size >= need_full) {
        float* Gf = (float*)(ws + off_gf_full);
        k_cast<<<16384, 256, 0, stream>>>(feat, featbf);
        k_gemm<<<dim3(6, 2048), 256, 0, stream>>>(featbf, Wf, bsum, Gf);
        k_rnn<float><<<64, 512, 0, stream>>>(lastc, W_ih, b_hh, W_proj, b_proj, Whh, Gf, out);
    } else if (ws_size >= need_tier2) {
        float* Gf = (float*)(ws + off_fb);
        k_gemm_legacy<float><<<dim3(6, 2048), 256, 0, stream>>>(feat, Wf, bsum, Gf);
        k_rnn<float><<<64, 512, 0, stream>>>(lastc, W_ih, b_hh, W_proj, b_proj, Whh, Gf, out);
    } else {
        u16* Gf = (u16*)(ws + off_fb);
        (void)need_tier3;
        k_gemm_legacy<u16><<<dim3(6, 2048), 256, 0, stream>>>(feat, Wf, bsum, Gf);
        k_rnn<u16><<<64, 512, 0, stream>>>(lastc, W_ih, b_hh, W_proj, b_proj, Whh, Gf, out);
    }
}